// Round 1
// baseline (143.612 us; speedup 1.0000x reference)
//
#include <hip/hip_runtime.h>

#define BN_EPS 1e-3f

// ---- order-preserving float<->uint key for atomicMax on floats ----
__device__ __forceinline__ unsigned int f2k(float f) {
    unsigned int u = __float_as_uint(f);
    return (u & 0x80000000u) ? ~u : (u | 0x80000000u);
}
__device__ __forceinline__ float k2f(unsigned int u) {
    return __uint_as_float((u & 0x80000000u) ? (u & 0x7FFFFFFFu) : ~u);
}

// Kernel 1: per-node precompute.
//   y[n,s,h]  = sum_f x[n,f] * Wk[s, f*H + h]
//   yb[n,h]   = sum_f x[n,f] * bk[f*H + h]
//   base[n,h] = sum_f x[n,f] * Wr[f,h] + br[h]
// One thread per (n, h); lanes over consecutive h -> coalesced Wk/bk/Wr reads.
template <int S, int F, int H>
__global__ void node_pre(const float* __restrict__ x,
                         const float* __restrict__ Wk,
                         const float* __restrict__ bk,
                         const float* __restrict__ Wr,
                         const float* __restrict__ br,
                         float* __restrict__ y,
                         float* __restrict__ yb,
                         float* __restrict__ base,
                         int N) {
    int t = blockIdx.x * blockDim.x + threadIdx.x;
    int n = t / H;
    int h = t % H;
    if (n >= N) return;

    float xf[F];
#pragma unroll
    for (int f = 0; f < F; ++f) xf[f] = x[n * F + f];

#pragma unroll
    for (int s = 0; s < S; ++s) {
        float acc = 0.f;
#pragma unroll
        for (int f = 0; f < F; ++f) acc += xf[f] * Wk[(s * F + f) * H + h];
        y[((size_t)n * S + s) * H + h] = acc;
    }

    float accb = 0.f, accr = 0.f;
#pragma unroll
    for (int f = 0; f < F; ++f) {
        accb += xf[f] * bk[f * H + h];
        accr += xf[f] * Wr[f * H + h];
    }
    yb[(size_t)n * H + h] = accb;
    base[(size_t)n * H + h] = accr + br[h];
}

// Kernel 2: per-edge message + scatter-add.
//   msg[e,h] = yb[src,h] + sum_s e[e,s] * y[src,s,h];  agg[dst,h] += msg
// One thread per (edge, h).
template <int S, int H>
__global__ void edge_scatter(const float* __restrict__ efeat,
                             const int* __restrict__ src,
                             const int* __restrict__ dst,
                             const float* __restrict__ y,
                             const float* __restrict__ yb,
                             float* __restrict__ agg,
                             int E) {
    int t = blockIdx.x * blockDim.x + threadIdx.x;
    int edge = t / H;
    int h = t % H;
    if (edge >= E) return;

    int sn = src[edge];
    int dn = dst[edge];

    // e row: 8 floats, 32B aligned -> two float4 loads (broadcast across the
    // H lanes of the same edge via L1).
    const float4* e4 = (const float4*)(efeat + (size_t)edge * S);
    float4 ea = e4[0];
    float4 eb = e4[1];
    float es[S] = {ea.x, ea.y, ea.z, ea.w, eb.x, eb.y, eb.z, eb.w};

    const float* yrow = y + (size_t)sn * S * H + h;
    float m = yb[(size_t)sn * H + h];
#pragma unroll
    for (int s = 0; s < S; ++s) m += es[s] * yrow[s * H];

    atomicAdd(&agg[(size_t)dn * H + h], m);
}

// Kernel 3: h = relu(agg + base); BN(inference); global max per h.
template <int H>
__global__ void bn_relu_max(const float* __restrict__ agg,
                            const float* __restrict__ base,
                            const float* __restrict__ gamma,
                            const float* __restrict__ beta,
                            const float* __restrict__ mmean,
                            const float* __restrict__ mvar,
                            unsigned int* __restrict__ pooled_u,
                            int N) {
    __shared__ unsigned int smax[H];
    if (threadIdx.x < H) smax[threadIdx.x] = 0u;
    __syncthreads();

    int t = blockIdx.x * blockDim.x + threadIdx.x;
    int stride = gridDim.x * blockDim.x;  // multiple of H (256-thread blocks)
    int h = t % H;

    float scale = gamma[h] * rsqrtf(mvar[h] + BN_EPS);
    float shift = beta[h] - mmean[h] * scale;

    float best = -INFINITY;
    int total = N * H;
    for (int i = t; i < total; i += stride) {
        float v = agg[i] + base[i];
        v = v > 0.f ? v : 0.f;          // relu
        v = v * scale + shift;          // BN (inference)
        best = fmaxf(best, v);
    }
    atomicMax(&smax[h], f2k(best));
    __syncthreads();
    if (threadIdx.x < H) atomicMax(&pooled_u[threadIdx.x], smax[threadIdx.x]);
}

// Kernel 4: out[j] = bd[j] + sum_h pooled[h] * Wd[h,j]
template <int H>
__global__ void final_matvec(const unsigned int* __restrict__ pooled_u,
                             const float* __restrict__ Wd,
                             const float* __restrict__ bd,
                             float* __restrict__ out,
                             int HOUT) {
    int j = threadIdx.x;
    if (j >= HOUT) return;
    float acc = bd[j];
#pragma unroll
    for (int hh = 0; hh < H; ++hh) acc += k2f(pooled_u[hh]) * Wd[hh * HOUT + j];
    out[j] = acc;
}

extern "C" void kernel_launch(void* const* d_in, const int* in_sizes, int n_in,
                              void* d_out, int out_size, void* d_ws, size_t ws_size,
                              hipStream_t stream) {
    const float* x     = (const float*)d_in[0];
    const float* e     = (const float*)d_in[1];
    const int*   src   = (const int*)d_in[2];
    const int*   dst   = (const int*)d_in[3];
    const float* Wk    = (const float*)d_in[4];
    const float* bk    = (const float*)d_in[5];
    const float* Wr    = (const float*)d_in[6];
    const float* br    = (const float*)d_in[7];
    const float* gamma = (const float*)d_in[8];
    const float* beta  = (const float*)d_in[9];
    const float* mmean = (const float*)d_in[10];
    const float* mvar  = (const float*)d_in[11];
    const float* Wd    = (const float*)d_in[12];
    const float* bd    = (const float*)d_in[13];

    constexpr int S = 8, F = 16, H = 16;
    const int E = in_sizes[2];
    const int N = in_sizes[0] / F;
    const int HOUT = in_sizes[13];  // 3

    // workspace layout
    float* y    = (float*)d_ws;                        // N*S*H
    float* yb   = y    + (size_t)N * S * H;            // N*H
    float* base = yb   + (size_t)N * H;                // N*H
    float* agg  = base + (size_t)N * H;                // N*H
    unsigned int* pooled_u = (unsigned int*)(agg + (size_t)N * H);  // H

    hipMemsetAsync(agg, 0, (size_t)N * H * sizeof(float), stream);
    hipMemsetAsync(pooled_u, 0, H * sizeof(unsigned int), stream);

    const int T = 256;
    int nh = N * H;
    node_pre<S, F, H><<<(nh + T - 1) / T, T, 0, stream>>>(x, Wk, bk, Wr, br, y, yb, base, N);

    long long eh = (long long)E * H;
    edge_scatter<S, H><<<(int)((eh + T - 1) / T), T, 0, stream>>>(e, src, dst, y, yb, agg, E);

    bn_relu_max<H><<<1024, T, 0, stream>>>(agg, base, gamma, beta, mmean, mvar, pooled_u, N);

    final_matvec<H><<<1, 64, 0, stream>>>(pooled_u, Wd, bd, (float*)d_out, HOUT);
}